// Round 4
// baseline (511.619 us; speedup 1.0000x reference)
//
#include <hip/hip_runtime.h>
#include <math.h>

// Invariant Point Attention, b=1, n=512, dim=384, pdim=128, H=8, SK=SV=16, PK=4, PV=8
#define NTOK 512
#define DIM 384
#define PDIM 128
#define H 8

#define QKB_STRIDE 224   // 128 scalar + 96 point (global frame)
#define VB_STRIDE  320   // 128 scalar + 192 point (global frame)
#define RES_STRIDE 1408  // 128 scalar | 192 point-local | 64 norms | 1024 pair
#define PART_STRIDE 1360 // 8 m | 8 l | 128 scalar | 192 point | 1024 pair (raw sums)
#define KS 4             // out-GEMM k-splits
#define KC (RES_STRIDE / KS)  // 352

static constexpr float SCALE_SCALAR = 0.14433756729740643f; // (3*16)^-0.5
static constexpr float SCALE_POINT  = 0.13608276348795434f; // (3*4*4.5)^-0.5
static constexpr float SCALE_PAIR   = 0.57735026918962580f; // 3^-0.5

// ---------------- Kernel 1: projections + frame transform ----------------
// grid (128 token-quads, 4 col-groups of 192), 192 threads.
__global__ __launch_bounds__(192) void ipa_proj(
    const float* __restrict__ x, const float* __restrict__ rot, const float* __restrict__ trans,
    const float* __restrict__ Wsq, const float* __restrict__ Wsk, const float* __restrict__ Wsv,
    const float* __restrict__ Wpq, const float* __restrict__ Wpk, const float* __restrict__ Wpv,
    float* __restrict__ qB, float* __restrict__ kB, float* __restrict__ vB)
{
  const int tt = blockIdx.x, cg = blockIdx.y, tid = threadIdx.x;
  __shared__ float s_x[4][DIM];    // 6 KB
  __shared__ float s_p[4][192];
  __shared__ float s_R[4][9];
  __shared__ float s_T[4][3];

  {
    const float4* xg = reinterpret_cast<const float4*>(x + (size_t)(tt * 4) * DIM);
    float4* sx4 = reinterpret_cast<float4*>(&s_x[0][0]);
    sx4[tid] = xg[tid];
    sx4[tid + 192] = xg[tid + 192];
  }
  if (tid < 36) s_R[tid / 9][tid % 9] = rot[(size_t)(tt * 4) * 9 + tid];
  if (tid >= 64 && tid < 76) s_T[(tid - 64) / 3][(tid - 64) % 3] = trans[(size_t)(tt * 4) * 3 + (tid - 64)];
  __syncthreads();

  const int c = cg * 192 + tid;
  const float* W; int ncols, lc;
  if      (c < 128) { W = Wsq; ncols = 128; lc = c; }
  else if (c < 256) { W = Wsk; ncols = 128; lc = c - 128; }
  else if (c < 384) { W = Wsv; ncols = 128; lc = c - 256; }
  else if (c < 480) { W = Wpq; ncols = 96;  lc = c - 384; }
  else if (c < 576) { W = Wpk; ncols = 96;  lc = c - 480; }
  else              { W = Wpv; ncols = 192; lc = c - 576; }

  float acc[4] = {};
  const float* wp = W + lc;
#pragma unroll 8
  for (int k = 0; k < DIM; ++k) {
    float w = *wp; wp += ncols;
#pragma unroll
    for (int tok = 0; tok < 4; ++tok) acc[tok] += w * s_x[tok][k];
  }

  if (cg < 2) {
#pragma unroll
    for (int tok = 0; tok < 4; ++tok) {
      const int i = tt * 4 + tok;
      if (c < 128)      qB[(size_t)i * QKB_STRIDE + c] = acc[tok];
      else if (c < 256) kB[(size_t)i * QKB_STRIDE + (c - 128)] = acc[tok];
      else              vB[(size_t)i * VB_STRIDE + (c - 256)] = acc[tok];
    }
  } else {
#pragma unroll
    for (int tok = 0; tok < 4; ++tok) s_p[tok][tid] = acc[tok];
    __syncthreads();
    for (int t = tid; t < 256; t += 192) {
      const int tok = t >> 6, tr = t & 63;
      const int i = tt * 4 + tok;
      const float* R = s_R[tok];
      const float* T = s_T[tok];
      const float* src; float* dst;
      if (cg == 2) {
        if (tr < 32) { src = &s_p[tok][tr * 3];             dst = qB + (size_t)i * QKB_STRIDE + 128 + tr * 3; }
        else         { src = &s_p[tok][96 + (tr - 32) * 3]; dst = kB + (size_t)i * QKB_STRIDE + 128 + (tr - 32) * 3; }
      } else {
        src = &s_p[tok][tr * 3]; dst = vB + (size_t)i * VB_STRIDE + 128 + tr * 3;
      }
      float px = src[0], py = src[1], pz = src[2];
#pragma unroll
      for (int r = 0; r < 3; ++r)
        dst[r] = px * R[0 * 3 + r] + py * R[1 * 3 + r] + pz * R[2 * 3 + r] + T[r];
    }
  }
}

// ---------------- Kernel 2a: single-pass online-softmax partial attention ----------------
// grid (NC, 512), 256 threads. No VGPR cap (spills were killing rounds 2-3).
__global__ __launch_bounds__(256) void ipa_attn_part(
    const float* __restrict__ pair, const float* __restrict__ pw,
    const float* __restrict__ Wpair, const float* __restrict__ bpair,
    const float* __restrict__ qB, const float* __restrict__ kB,
    const float* __restrict__ vB, float* __restrict__ partial,
    int NC, int JR, int NT)
{
  const int c = blockIdx.x, i = blockIdx.y, tid = threadIdx.x;

  __shared__ float4 s_pT4[2048];        // 32 KB pair tile (swizzled [d4][jl^(d4&7)])
  __shared__ float  s_wpT[H][PDIM];     // 4 KB  Wpair^T * SCALE_PAIR
  __shared__ float  s_e[4][2][64];      // 2 KB  per-wave e values
  __shared__ float  s_qs[128];
  __shared__ float  s_qp[96];
  __shared__ float  s_coef[H], s_bp[H];

  for (int t = tid; t < PDIM * H; t += 256) {
    const int h = t >> 7, d = t & 127;
    s_wpT[h][d] = Wpair[d * 8 + h] * SCALE_PAIR;
  }
  if (tid < 224) {
    float v = qB[(size_t)i * QKB_STRIDE + tid];
    if (tid < 128) s_qs[tid] = v; else s_qp[tid - 128] = v;
  }
  if (tid < H) {
    s_coef[tid] = -0.5f * log1pf(__expf(pw[tid])) * SCALE_POINT;  // softplus
    s_bp[tid]   = bpair[tid] * SCALE_PAIR;
  }

  // roles (all within one wave per head-pair):
  const int hp = tid >> 6, jl = tid & 63;          // logit role
  const int h0 = 2 * hp, h1 = h0 + 1;
  const int h = tid >> 5, u = tid & 31;            // aggregation role
  const int ovb0 = (u < 16) ? (h * 16 + u) : (128 + h * 24 + (u - 16));
  const int ovb1 = 128 + h * 24 + 16 + u;          // used when u < 8

  float m0 = -1e30f, m1 = -1e30f, l0 = 0.f, l1 = 0.f;
  float4 accp = make_float4(0.f, 0.f, 0.f, 0.f);
  float accv0 = 0.f, accv1 = 0.f;

  for (int t = 0; t < NT; ++t) {
    // stage tile (global -> regs -> swizzled LDS)
    float4 r[8];
    {
      const float4* g = reinterpret_cast<const float4*>(
          pair + ((size_t)i * NTOK + (size_t)c * JR + (size_t)t * 64) * PDIM);
#pragma unroll
      for (int k = 0; k < 8; ++k) r[k] = g[tid + 256 * k];
    }
    __syncthreads();   // previous tile fully consumed
#pragma unroll
    for (int k = 0; k < 8; ++k) {
      const int f = tid + 256 * k;
      s_pT4[(f & 31) * 64 + ((f >> 5) ^ (f & 7))] = r[k];
    }
    __syncthreads();   // tile (and, on t==0, the init stores) visible

    // ---- logits for row jl, heads h0,h1 (float4 accumulator chains for ILP) ----
    float4 pa0v = make_float4(0.f, 0.f, 0.f, 0.f), pa1v = pa0v;
    {
      const float4* w0p = reinterpret_cast<const float4*>(&s_wpT[h0][0]);
      const float4* w1p = reinterpret_cast<const float4*>(&s_wpT[h1][0]);
#pragma unroll 8
      for (int d4 = 0; d4 < 32; ++d4) {
        float4 p = s_pT4[d4 * 64 + (jl ^ (d4 & 7))];
        float4 w0 = w0p[d4], w1 = w1p[d4];
        pa0v.x += p.x * w0.x; pa0v.y += p.y * w0.y; pa0v.z += p.z * w0.z; pa0v.w += p.w * w0.w;
        pa1v.x += p.x * w1.x; pa1v.y += p.y * w1.y; pa1v.z += p.z * w1.z; pa1v.w += p.w * w1.w;
      }
    }
    const float pa0 = pa0v.x + pa0v.y + pa0v.z + pa0v.w;
    const float pa1 = pa1v.x + pa1v.y + pa1v.z + pa1v.w;

    const int j = c * JR + t * 64 + jl;
    const float4* kr4 = reinterpret_cast<const float4*>(kB + (size_t)j * QKB_STRIDE);
    float sa0 = 0.f, sa1 = 0.f;
    {
      const float4* qs4 = reinterpret_cast<const float4*>(s_qs);
#pragma unroll
      for (int tq = 0; tq < 4; ++tq) {
        float4 q = qs4[h0 * 4 + tq], k = kr4[h0 * 4 + tq];
        sa0 += q.x * k.x + q.y * k.y + q.z * k.z + q.w * k.w;
        float4 q2 = qs4[h1 * 4 + tq], k2 = kr4[h1 * 4 + tq];
        sa1 += q2.x * k2.x + q2.y * k2.y + q2.z * k2.z + q2.w * k2.w;
      }
    }
    float da0 = 0.f, da1 = 0.f;
    {
      const float4* qp4 = reinterpret_cast<const float4*>(s_qp);
#pragma unroll
      for (int tq = 0; tq < 3; ++tq) {
        float4 q = qp4[h0 * 3 + tq], k = kr4[32 + h0 * 3 + tq];
        float d0 = q.x - k.x, d1 = q.y - k.y, d2 = q.z - k.z, d3 = q.w - k.w;
        da0 += d0 * d0 + d1 * d1 + d2 * d2 + d3 * d3;
        float4 q2 = qp4[h1 * 3 + tq], k2 = kr4[32 + h1 * 3 + tq];
        float e0d = q2.x - k2.x, e1d = q2.y - k2.y, e2d = q2.z - k2.z, e3d = q2.w - k2.w;
        da1 += e0d * e0d + e1d * e1d + e2d * e2d + e3d * e3d;
      }
    }
    float lg0 = sa0 * SCALE_SCALAR + s_coef[h0] * da0 + pa0 + s_bp[h0];
    float lg1 = sa1 * SCALE_SCALAR + s_coef[h1] * da1 + pa1 + s_bp[h1];

    // ---- online softmax update (width-64, stays in wave) ----
    float tm0 = lg0, tm1 = lg1;
#pragma unroll
    for (int off = 32; off; off >>= 1) {
      tm0 = fmaxf(tm0, __shfl_xor(tm0, off, 64));
      tm1 = fmaxf(tm1, __shfl_xor(tm1, off, 64));
    }
    const float m0n = fmaxf(m0, tm0), m1n = fmaxf(m1, tm1);
    const float sc0 = __expf(m0 - m0n), sc1 = __expf(m1 - m1n);
    const float e0 = __expf(lg0 - m0n), e1 = __expf(lg1 - m1n);
    float ts0 = e0, ts1 = e1;
#pragma unroll
    for (int off = 32; off; off >>= 1) {
      ts0 += __shfl_xor(ts0, off, 64);
      ts1 += __shfl_xor(ts1, off, 64);
    }
    m0 = m0n; m1 = m1n;
    l0 = l0 * sc0 + ts0;
    l1 = l1 * sc1 + ts1;
    s_e[hp][0][jl] = e0;   // same-wave write/read: no barrier needed
    s_e[hp][1][jl] = e1;

    // ---- rescale + aggregate from LDS tile and L2-hot vB ----
    const float sc = (tid & 32) ? sc1 : sc0;
    accp.x *= sc; accp.y *= sc; accp.z *= sc; accp.w *= sc;
    accv0 *= sc; accv1 *= sc;
    const float* erow = &s_e[hp][(tid >> 5) & 1][0];
    const float* vrow = vB + (size_t)(c * JR + t * 64) * VB_STRIDE;
#pragma unroll 8
    for (int j2 = 0; j2 < 64; ++j2) {
      const float e = erow[j2];
      float4 p = s_pT4[u * 64 + (j2 ^ (u & 7))];
      accp.x += e * p.x; accp.y += e * p.y; accp.z += e * p.z; accp.w += e * p.w;
      accv0 += e * vrow[ovb0];
      if (u < 8) accv1 += e * vrow[ovb1];
      vrow += VB_STRIDE;
    }
  }

  // ---- write partial ----
  float* part = partial + ((size_t)i * NC + c) * PART_STRIDE;
  if ((tid & 63) == 0) {
    part[h0] = m0; part[h1] = m1;
    part[8 + h0] = l0; part[8 + h1] = l1;
  }
  *reinterpret_cast<float4*>(part + 336 + h * 128 + u * 4) = accp;
  if (u < 16) part[16 + h * 16 + u] = accv0;
  else        part[144 + h * 24 + (u - 16)] = accv0;
  if (u < 8)  part[144 + h * 24 + 16 + u] = accv1;
}

// ---------------- Kernel 2b: split-softmax combine + epilogue ----------------
__global__ __launch_bounds__(256) void ipa_combine(
    const float* __restrict__ partial, const float* __restrict__ rot,
    const float* __restrict__ trans, float* __restrict__ results, int NC)
{
  const int i = blockIdx.x, tid = threadIdx.x;
  __shared__ float s_f[8][H];
  __shared__ float s_invL[H];
  __shared__ float s_res[RES_STRIDE];
  __shared__ float s_pt[192];
  __shared__ float s_R[9], s_T[3];

  const float* pb = partial + (size_t)i * NC * PART_STRIDE;
  if (tid < H) {
    float M = -1e30f;
    for (int cc = 0; cc < NC; ++cc) M = fmaxf(M, pb[cc * PART_STRIDE + tid]);
    float L = 0.f;
    for (int cc = 0; cc < NC; ++cc) {
      float f = __expf(pb[cc * PART_STRIDE + tid] - M);
      s_f[cc][tid] = f;
      L += f * pb[cc * PART_STRIDE + 8 + tid];
    }
    s_invL[tid] = 1.f / L;
  }
  if (tid >= 32 && tid < 41) s_R[tid - 32] = rot[i * 9 + (tid - 32)];
  if (tid >= 48 && tid < 51) s_T[tid - 48] = trans[i * 3 + (tid - 48)];
  __syncthreads();

  for (int idx = tid; idx < 1344; idx += 256) {
    int hh, ofs;
    if (idx < 128)      { hh = idx >> 4;          ofs = 16 + idx; }
    else if (idx < 320) { hh = (idx - 128) / 24;  ofs = 144 + (idx - 128); }
    else                { hh = (idx - 320) >> 7;  ofs = 336 + (idx - 320); }
    float v = 0.f;
    for (int cc = 0; cc < NC; ++cc) v += s_f[cc][hh] * pb[cc * PART_STRIDE + ofs];
    v *= s_invL[hh];
    if (idx < 128)      s_res[idx] = v;
    else if (idx < 320) s_pt[idx - 128] = v;
    else                s_res[384 + (idx - 320)] = v;
  }
  __syncthreads();

  if (tid < 64) {
    const int hh = tid >> 3, p = tid & 7;
    const int base = hh * 24 + p * 3;
    float gx = s_pt[base]     - s_T[0];
    float gy = s_pt[base + 1] - s_T[1];
    float gz = s_pt[base + 2] - s_T[2];
    float lx = gx * s_R[0] + gy * s_R[1] + gz * s_R[2];
    float ly = gx * s_R[3] + gy * s_R[4] + gz * s_R[5];
    float lz = gx * s_R[6] + gy * s_R[7] + gz * s_R[8];
    s_res[128 + base]     = lx;
    s_res[128 + base + 1] = ly;
    s_res[128 + base + 2] = lz;
    s_res[320 + hh * 8 + p] = sqrtf(lx * lx + ly * ly + lz * lz + 1e-8f);
  }
  __syncthreads();

  float4* dst = reinterpret_cast<float4*>(results + (size_t)i * RES_STRIDE);
  const float4* src = reinterpret_cast<const float4*>(s_res);
  for (int t = tid; t < RES_STRIDE / 4; t += 256) dst[t] = src[t];
}

// ---------------- Kernel 3a: split-K GEMM partials ----------------
// grid (16 tok-tiles of 32, 6 col-tiles of 64, KS), 256 threads; 8 acc/thread.
__global__ __launch_bounds__(256) void ipa_out1(
    const float* __restrict__ results, const float* __restrict__ Wout,
    float* __restrict__ pout)
{
  const int tt = blockIdx.x, ct = blockIdx.y, ks = blockIdx.z, tid = threadIdx.x;
  __shared__ float s_a[32][40];   // 5 KB  (stride 40: 16B-aligned rows, bank-spread)
  __shared__ float s_w[32][64];   // 8 KB
  const int tx = tid & 15, ty = tid >> 4;
  float acc[2][4] = {};

  for (int kc = 0; kc < KC / 32; ++kc) {
    const int k0 = ks * KC + kc * 32;
    __syncthreads();
    {
      const int tok = tid >> 3, kq = tid & 7;
      *reinterpret_cast<float4*>(&s_a[tok][kq * 4]) =
          *reinterpret_cast<const float4*>(results + (size_t)(tt * 32 + tok) * RES_STRIDE + k0 + kq * 4);
    }
#pragma unroll
    for (int rr = 0; rr < 2; ++rr) {
      const int tq = tid + rr * 256;
      const int kk = tq >> 4, c4 = tq & 15;
      *reinterpret_cast<float4*>(&s_w[kk][c4 * 4]) =
          *reinterpret_cast<const float4*>(Wout + (size_t)(k0 + kk) * DIM + ct * 64 + c4 * 4);
    }
    __syncthreads();
#pragma unroll 8
    for (int kk = 0; kk < 32; ++kk) {
      const float a0 = s_a[ty][kk], a1 = s_a[ty + 16][kk];
#pragma unroll
      for (int cc = 0; cc < 4; ++cc) {
        const float w = s_w[kk][tx + 16 * cc];
        acc[0][cc] += a0 * w;
        acc[1][cc] += a1 * w;
      }
    }
  }
#pragma unroll
  for (int rr = 0; rr < 2; ++rr)
#pragma unroll
    for (int cc = 0; cc < 4; ++cc)
      pout[((size_t)ks * NTOK + tt * 32 + ty + 16 * rr) * DIM + ct * 64 + tx + 16 * cc] = acc[rr][cc];
}

// ---------------- Kernel 3b: reduce k-splits + bias ----------------
__global__ __launch_bounds__(256) void ipa_out2(
    const float* __restrict__ pout, const float* __restrict__ bout, float* __restrict__ out)
{
  const int idx = blockIdx.x * 256 + threadIdx.x;      // 49152 float4s
  const float4* p4 = reinterpret_cast<const float4*>(pout);
  float4 v = p4[idx];
#pragma unroll
  for (int ks = 1; ks < KS; ++ks) {
    float4 w = p4[idx + ks * (NTOK * DIM / 4)];
    v.x += w.x; v.y += w.y; v.z += w.z; v.w += w.w;
  }
  const float4 b = reinterpret_cast<const float4*>(bout)[idx % (DIM / 4)];
  v.x += b.x; v.y += b.y; v.z += b.z; v.w += b.w;
  reinterpret_cast<float4*>(out)[idx] = v;
}

// ---------------- launch ----------------
extern "C" void kernel_launch(void* const* d_in, const int* in_sizes, int n_in,
                              void* d_out, int out_size, void* d_ws, size_t ws_size,
                              hipStream_t stream) {
  const float* x     = (const float*)d_in[0];
  const float* pair  = (const float*)d_in[1];
  const float* rot   = (const float*)d_in[2];
  const float* trans = (const float*)d_in[3];
  const float* Wsq   = (const float*)d_in[4];
  const float* Wsk   = (const float*)d_in[5];
  const float* Wsv   = (const float*)d_in[6];
  const float* Wpq   = (const float*)d_in[7];
  const float* Wpk   = (const float*)d_in[8];
  const float* Wpv   = (const float*)d_in[9];
  const float* pw    = (const float*)d_in[10];
  const float* Wpair = (const float*)d_in[11];
  const float* bpair = (const float*)d_in[12];
  const float* Wout  = (const float*)d_in[13];
  const float* bout  = (const float*)d_in[14];
  float* out = (float*)d_out;

  float* ws = (float*)d_ws;
  float* qB = ws;                                     // 512*224
  float* kB = qB + (size_t)NTOK * QKB_STRIDE;         // 512*224
  float* vB = kB + (size_t)NTOK * QKB_STRIDE;         // 512*320
  float* results = vB + (size_t)NTOK * VB_STRIDE;     // 512*1408
  float* partial = results + (size_t)NTOK * RES_STRIDE;
  float* pout = partial;                              // aliases partial (dead after combine)

  const size_t base_f = (size_t)NTOK * QKB_STRIDE * 2 + (size_t)NTOK * VB_STRIDE
                      + (size_t)NTOK * RES_STRIDE;
  const size_t pout_f = (size_t)KS * NTOK * DIM;      // 786432
  int NC = 8;
  while (NC > 1) {
    size_t region = (size_t)NTOK * NC * PART_STRIDE;
    if (region < pout_f) region = pout_f;
    if ((base_f + region) * 4 <= ws_size) break;
    NC >>= 1;
  }
  const int JR = NTOK / NC;
  const int NT = JR / 64;

  ipa_proj<<<dim3(NTOK / 4, 4), 192, 0, stream>>>(x, rot, trans, Wsq, Wsk, Wsv, Wpq, Wpk, Wpv, qB, kB, vB);
  ipa_attn_part<<<dim3(NC, NTOK), 256, 0, stream>>>(pair, pw, Wpair, bpair, qB, kB, vB, partial, NC, JR, NT);
  ipa_combine<<<NTOK, 256, 0, stream>>>(partial, rot, trans, results, NC);
  ipa_out1<<<dim3(NTOK / 32, DIM / 64, KS), 256, 0, stream>>>(results, Wout, pout);
  ipa_out2<<<NTOK * DIM / 4 / 256, 256, 0, stream>>>(pout, bout, out);
}

// Round 5
// 430.637 us; speedup vs baseline: 1.1881x; 1.1881x over previous
//
#include <hip/hip_runtime.h>
#include <math.h>

// Invariant Point Attention, b=1, n=512, dim=384, pdim=128, H=8, SK=SV=16, PK=4, PV=8
#define NTOK 512
#define DIM 384
#define PDIM 128
#define H 8
#define NC 8             // j-chunks (static; 512/8 = 64-row tile, NT=1)

#define QKB_STRIDE 224   // 128 scalar + 96 point (global frame)
#define VB_STRIDE  320   // 128 scalar + 192 point (global frame)
#define RES_STRIDE 1408  // 128 scalar | 192 point-local | 64 norms | 1024 pair
#define PART_STRIDE 1360 // 8 m | 8 l | 128 scalar | 192 point | 1024 pair (raw sums)
#define KS 8             // out-GEMM k-splits
#define KC (RES_STRIDE / KS)  // 176

static constexpr float SCALE_SCALAR = 0.14433756729740643f; // (3*16)^-0.5
static constexpr float SCALE_POINT  = 0.13608276348795434f; // (3*4*4.5)^-0.5
static constexpr float SCALE_PAIR   = 0.57735026918962580f; // 3^-0.5

// ---------------- Kernel 1: projections + frame transform ----------------
__global__ __launch_bounds__(192) void ipa_proj(
    const float* __restrict__ x, const float* __restrict__ rot, const float* __restrict__ trans,
    const float* __restrict__ Wsq, const float* __restrict__ Wsk, const float* __restrict__ Wsv,
    const float* __restrict__ Wpq, const float* __restrict__ Wpk, const float* __restrict__ Wpv,
    float* __restrict__ qB, float* __restrict__ kB, float* __restrict__ vB)
{
  const int tt = blockIdx.x, cg = blockIdx.y, tid = threadIdx.x;
  __shared__ float s_x[4][DIM];
  __shared__ float s_p[4][192];
  __shared__ float s_R[4][9];
  __shared__ float s_T[4][3];

  {
    const float4* xg = reinterpret_cast<const float4*>(x + (size_t)(tt * 4) * DIM);
    float4* sx4 = reinterpret_cast<float4*>(&s_x[0][0]);
    sx4[tid] = xg[tid];
    sx4[tid + 192] = xg[tid + 192];
  }
  if (tid < 36) s_R[tid / 9][tid % 9] = rot[(size_t)(tt * 4) * 9 + tid];
  if (tid >= 64 && tid < 76) s_T[(tid - 64) / 3][(tid - 64) % 3] = trans[(size_t)(tt * 4) * 3 + (tid - 64)];
  __syncthreads();

  const int c = cg * 192 + tid;
  const float* W; int ncols, lc;
  if      (c < 128) { W = Wsq; ncols = 128; lc = c; }
  else if (c < 256) { W = Wsk; ncols = 128; lc = c - 128; }
  else if (c < 384) { W = Wsv; ncols = 128; lc = c - 256; }
  else if (c < 480) { W = Wpq; ncols = 96;  lc = c - 384; }
  else if (c < 576) { W = Wpk; ncols = 96;  lc = c - 480; }
  else              { W = Wpv; ncols = 192; lc = c - 576; }

  float acc[4] = {};
  const float* wp = W + lc;
#pragma unroll 8
  for (int k = 0; k < DIM; ++k) {
    float w = *wp; wp += ncols;
#pragma unroll
    for (int tok = 0; tok < 4; ++tok) acc[tok] += w * s_x[tok][k];
  }

  if (cg < 2) {
#pragma unroll
    for (int tok = 0; tok < 4; ++tok) {
      const int i = tt * 4 + tok;
      if (c < 128)      qB[(size_t)i * QKB_STRIDE + c] = acc[tok];
      else if (c < 256) kB[(size_t)i * QKB_STRIDE + (c - 128)] = acc[tok];
      else              vB[(size_t)i * VB_STRIDE + (c - 256)] = acc[tok];
    }
  } else {
#pragma unroll
    for (int tok = 0; tok < 4; ++tok) s_p[tok][tid] = acc[tok];
    __syncthreads();
    for (int t = tid; t < 256; t += 192) {
      const int tok = t >> 6, tr = t & 63;
      const int i = tt * 4 + tok;
      const float* R = s_R[tok];
      const float* T = s_T[tok];
      const float* src; float* dst;
      if (cg == 2) {
        if (tr < 32) { src = &s_p[tok][tr * 3];             dst = qB + (size_t)i * QKB_STRIDE + 128 + tr * 3; }
        else         { src = &s_p[tok][96 + (tr - 32) * 3]; dst = kB + (size_t)i * QKB_STRIDE + 128 + (tr - 32) * 3; }
      } else {
        src = &s_p[tok][tr * 3]; dst = vB + (size_t)i * VB_STRIDE + 128 + tr * 3;
      }
      float px = src[0], py = src[1], pz = src[2];
#pragma unroll
      for (int r = 0; r < 3; ++r)
        dst[r] = px * R[0 * 3 + r] + py * R[1 * 3 + r] + pz * R[2 * 3 + r] + T[r];
    }
  }
}

// ---------------- Kernel 2a: single-tile partial attention (NT=1) ----------------
// grid (NC, 512), 256 threads. Pair tile DMA'd global->LDS (linear layout, coalesced);
// logit read uses lane-permuted d4 order (bank-spread); agg reads are contiguous.
__global__ __launch_bounds__(256) void ipa_attn_part(
    const float* __restrict__ pair, const float* __restrict__ pw,
    const float* __restrict__ Wpair, const float* __restrict__ bpair,
    const float* __restrict__ qB, const float* __restrict__ kB,
    const float* __restrict__ vB, float* __restrict__ partial)
{
  const int c = blockIdx.x, i = blockIdx.y, tid = threadIdx.x;

  __shared__ float4 s_pT4[2048];        // 32 KB pair tile, LINEAR [jl][d4]
  __shared__ float  s_wpT[H][PDIM];     // 4 KB  Wpair^T * SCALE_PAIR
  __shared__ float  s_e[H][65];         // ~2 KB (pad 65: bank-spread for per-head reads)
  __shared__ float  s_lm[16];           // m[8] | l[8]
  __shared__ float  s_coef[H], s_bp[H];

  const int wv = tid >> 6, ln = tid & 63;
  const int h0 = 2 * wv, h1 = h0 + 1;

  // ---- A: scalar + point-distance logit parts straight from global (L2-hot) ----
  const float4* kbase = reinterpret_cast<const float4*>(kB + (size_t)(c * 64 + ln) * QKB_STRIDE);
  const float4* qbase = reinterpret_cast<const float4*>(qB + (size_t)i * QKB_STRIDE);
  float sa0 = 0.f, sa1 = 0.f, da0 = 0.f, da1 = 0.f;
#pragma unroll
  for (int t = 0; t < 4; ++t) {
    float4 q = qbase[h0 * 4 + t], k = kbase[h0 * 4 + t];
    sa0 += q.x * k.x + q.y * k.y + q.z * k.z + q.w * k.w;
    float4 q2 = qbase[h1 * 4 + t], k2 = kbase[h1 * 4 + t];
    sa1 += q2.x * k2.x + q2.y * k2.y + q2.z * k2.z + q2.w * k2.w;
  }
#pragma unroll
  for (int t = 0; t < 3; ++t) {
    float4 q = qbase[32 + h0 * 3 + t], k = kbase[32 + h0 * 3 + t];
    float d0 = q.x - k.x, d1 = q.y - k.y, d2 = q.z - k.z, d3 = q.w - k.w;
    da0 += d0 * d0 + d1 * d1 + d2 * d2 + d3 * d3;
    float4 q2 = qbase[32 + h1 * 3 + t], k2 = kbase[32 + h1 * 3 + t];
    float e0 = q2.x - k2.x, e1 = q2.y - k2.y, e2 = q2.z - k2.z, e3 = q2.w - k2.w;
    da1 += e0 * e0 + e1 * e1 + e2 * e2 + e3 * e3;
  }

  // ---- B: async DMA of the 64x128 pair tile into LDS (linear, coalesced) ----
  const float4* gsrc = reinterpret_cast<const float4*>(pair + ((size_t)i * NTOK + (size_t)c * 64) * PDIM);
#if defined(__has_builtin) && __has_builtin(__builtin_amdgcn_global_load_lds)
#pragma unroll
  for (int w = 0; w < 8; ++w) {
    __builtin_amdgcn_global_load_lds(
        (const __attribute__((address_space(1))) float4*)(gsrc + ((wv * 8 + w) * 64 + ln)),
        (__attribute__((address_space(3))) float4*)(&s_pT4[(wv * 8 + w) * 64]), 16, 0, 0);
  }
#else
#pragma unroll
  for (int w = 0; w < 8; ++w) {
    const int s = (wv * 8 + w) * 64 + ln;
    s_pT4[s] = gsrc[s];
  }
#endif

  // ---- C: stage Wpair^T and small constants ----
  for (int t = tid; t < PDIM * H; t += 256) {
    const int d = t >> 3, h = t & 7;
    s_wpT[h][d] = Wpair[t] * SCALE_PAIR;   // Wpair[d*8+h]
  }
  if (tid < H) {
    s_coef[tid] = -0.5f * log1pf(__expf(pw[tid])) * SCALE_POINT;  // softplus
    s_bp[tid]   = bpair[tid] * SCALE_PAIR;
  }
  __syncthreads();   // DMA drained (vmcnt 0) + staging visible

  // ---- D: pair-bias logits from LDS (lane-permuted d4 order) + total logit ----
  float pa0 = 0.f, pa1 = 0.f;
  {
    const int xo = ln & 7;
    const float4* w0p = reinterpret_cast<const float4*>(&s_wpT[h0][0]);
    const float4* w1p = reinterpret_cast<const float4*>(&s_wpT[h1][0]);
#pragma unroll 8
    for (int t = 0; t < 32; ++t) {
      const int d4 = t ^ xo;
      float4 p = s_pT4[ln * 32 + d4];
      float4 w0 = w0p[d4], w1 = w1p[d4];
      pa0 += p.x * w0.x + p.y * w0.y + p.z * w0.z + p.w * w0.w;
      pa1 += p.x * w1.x + p.y * w1.y + p.z * w1.z + p.w * w1.w;
    }
  }
  float lg0 = sa0 * SCALE_SCALAR + s_coef[h0] * da0 + pa0 + s_bp[h0];
  float lg1 = sa1 * SCALE_SCALAR + s_coef[h1] * da1 + pa1 + s_bp[h1];

  // ---- E: softmax over the 64-row tile (width-64, in-wave) ----
  float m0 = lg0, m1 = lg1;
#pragma unroll
  for (int off = 32; off; off >>= 1) {
    m0 = fmaxf(m0, __shfl_xor(m0, off, 64));
    m1 = fmaxf(m1, __shfl_xor(m1, off, 64));
  }
  const float e0 = __expf(lg0 - m0), e1 = __expf(lg1 - m1);
  float l0 = e0, l1 = e1;
#pragma unroll
  for (int off = 32; off; off >>= 1) {
    l0 += __shfl_xor(l0, off, 64);
    l1 += __shfl_xor(l1, off, 64);
  }
  s_e[h0][ln] = e0;
  s_e[h1][ln] = e1;
  if (ln == 0) {
    s_lm[h0] = m0; s_lm[h1] = m1;
    s_lm[8 + h0] = l0; s_lm[8 + h1] = l1;
  }
  __syncthreads();   // e-table visible to all waves

  float* part = partial + ((size_t)i * NC + c) * PART_STRIDE;

  // ---- F: pair aggregation (contiguous LDS reads, broadcast e) ----
  {
    const int h = tid >> 5, u = tid & 31;
    float4 accp = make_float4(0.f, 0.f, 0.f, 0.f);
#pragma unroll 8
    for (int j2 = 0; j2 < 64; ++j2) {
      const float e = s_e[h][j2];
      float4 p = s_pT4[j2 * 32 + u];
      accp.x += e * p.x; accp.y += e * p.y; accp.z += e * p.z; accp.w += e * p.w;
    }
    *reinterpret_cast<float4*>(part + 336 + h * 128 + u * 4) = accp;
  }

  // ---- G: v aggregation (coalesced float4 reads of vB) ----
  if (tid < 80) {
    const int col4 = tid;
    const int hv = (col4 < 32) ? (col4 >> 2) : (col4 - 32) / 6;
    const float4* vb4 = reinterpret_cast<const float4*>(vB) + (size_t)(c * 64) * 80 + col4;
    float4 accv = make_float4(0.f, 0.f, 0.f, 0.f);
#pragma unroll 8
    for (int j2 = 0; j2 < 64; ++j2) {
      const float e = s_e[hv][j2];
      float4 v = vb4[(size_t)j2 * 80];
      accv.x += e * v.x; accv.y += e * v.y; accv.z += e * v.z; accv.w += e * v.w;
    }
    *reinterpret_cast<float4*>(part + 16 + col4 * 4) = accv;
  }

  // ---- H: m/l ----
  if (tid < 16) part[tid] = s_lm[tid];
}

// ---------------- Kernel 2b: split-softmax combine + epilogue ----------------
__global__ __launch_bounds__(256) void ipa_combine(
    const float* __restrict__ partial, const float* __restrict__ rot,
    const float* __restrict__ trans, float* __restrict__ results)
{
  const int i = blockIdx.x, tid = threadIdx.x;
  __shared__ float s_f[NC][H];
  __shared__ float s_invL[H];
  __shared__ float s_res[RES_STRIDE];
  __shared__ float s_pt[192];
  __shared__ float s_R[9], s_T[3];

  const float* pb = partial + (size_t)i * NC * PART_STRIDE;
  if (tid < H) {
    float M = -1e30f;
    for (int cc = 0; cc < NC; ++cc) M = fmaxf(M, pb[cc * PART_STRIDE + tid]);
    float L = 0.f;
    for (int cc = 0; cc < NC; ++cc) {
      float f = __expf(pb[cc * PART_STRIDE + tid] - M);
      s_f[cc][tid] = f;
      L += f * pb[cc * PART_STRIDE + 8 + tid];
    }
    s_invL[tid] = 1.f / L;
  }
  if (tid >= 32 && tid < 41) s_R[tid - 32] = rot[i * 9 + (tid - 32)];
  if (tid >= 48 && tid < 51) s_T[tid - 48] = trans[i * 3 + (tid - 48)];
  __syncthreads();

  for (int idx = tid; idx < 1344; idx += 256) {
    int hh, ofs;
    if (idx < 128)      { hh = idx >> 4;          ofs = 16 + idx; }
    else if (idx < 320) { hh = (idx - 128) / 24;  ofs = 144 + (idx - 128); }
    else                { hh = (idx - 320) >> 7;  ofs = 336 + (idx - 320); }
    float v = 0.f;
#pragma unroll
    for (int cc = 0; cc < NC; ++cc) v += s_f[cc][hh] * pb[cc * PART_STRIDE + ofs];
    v *= s_invL[hh];
    if (idx < 128)      s_res[idx] = v;
    else if (idx < 320) s_pt[idx - 128] = v;
    else                s_res[384 + (idx - 320)] = v;
  }
  __syncthreads();

  if (tid < 64) {
    const int hh = tid >> 3, p = tid & 7;
    const int base = hh * 24 + p * 3;
    float gx = s_pt[base]     - s_T[0];
    float gy = s_pt[base + 1] - s_T[1];
    float gz = s_pt[base + 2] - s_T[2];
    float lx = gx * s_R[0] + gy * s_R[1] + gz * s_R[2];
    float ly = gx * s_R[3] + gy * s_R[4] + gz * s_R[5];
    float lz = gx * s_R[6] + gy * s_R[7] + gz * s_R[8];
    s_res[128 + base]     = lx;
    s_res[128 + base + 1] = ly;
    s_res[128 + base + 2] = lz;
    s_res[320 + hh * 8 + p] = sqrtf(lx * lx + ly * ly + lz * lz + 1e-8f);
  }
  __syncthreads();

  float4* dst = reinterpret_cast<float4*>(results + (size_t)i * RES_STRIDE);
  const float4* src = reinterpret_cast<const float4*>(s_res);
  for (int t = tid; t < RES_STRIDE / 4; t += 256) dst[t] = src[t];
}

// ---------------- Kernel 3a: split-K GEMM partials ----------------
// grid (16, 6, KS=8), 256 threads; 32x64 tile, K chunk = 176 in 11 steps of 16.
__global__ __launch_bounds__(256) void ipa_out1(
    const float* __restrict__ results, const float* __restrict__ Wout,
    float* __restrict__ pout)
{
  const int tt = blockIdx.x, ct = blockIdx.y, ks = blockIdx.z, tid = threadIdx.x;
  __shared__ float s_a[32][20];   // 2.5 KB (20-float rows: 16B-aligned, bank-spread)
  __shared__ float s_w[16][64];   // 4 KB
  const int tx = tid & 15, ty = tid >> 4;
  float acc[2][4] = {};

  for (int kc = 0; kc < 11; ++kc) {
    const int k0 = ks * KC + kc * 16;
    __syncthreads();
    if (tid < 128) {
      const int row = tid >> 2, kq = tid & 3;
      *reinterpret_cast<float4*>(&s_a[row][kq * 4]) =
          *reinterpret_cast<const float4*>(results + (size_t)(tt * 32 + row) * RES_STRIDE + k0 + kq * 4);
    }
    {
      const int kk = tid >> 4, c4 = tid & 15;
      *reinterpret_cast<float4*>(&s_w[kk][c4 * 4]) =
          *reinterpret_cast<const float4*>(Wout + (size_t)(k0 + kk) * DIM + ct * 64 + c4 * 4);
    }
    __syncthreads();
#pragma unroll
    for (int kk = 0; kk < 16; ++kk) {
      const float a0 = s_a[ty][kk], a1 = s_a[ty + 16][kk];
#pragma unroll
      for (int cc = 0; cc < 4; ++cc) {
        const float w = s_w[kk][tx + 16 * cc];
        acc[0][cc] += a0 * w;
        acc[1][cc] += a1 * w;
      }
    }
  }
#pragma unroll
  for (int rr = 0; rr < 2; ++rr)
#pragma unroll
    for (int cc = 0; cc < 4; ++cc)
      pout[((size_t)ks * NTOK + tt * 32 + ty + 16 * rr) * DIM + ct * 64 + tx + 16 * cc] = acc[rr][cc];
}

// ---------------- Kernel 3b: reduce k-splits + bias ----------------
__global__ __launch_bounds__(256) void ipa_out2(
    const float* __restrict__ pout, const float* __restrict__ bout, float* __restrict__ out)
{
  const int idx = blockIdx.x * 256 + threadIdx.x;      // 49152 float4s
  const float4* p4 = reinterpret_cast<const float4*>(pout);
  float4 v = p4[idx];
#pragma unroll
  for (int ks = 1; ks < KS; ++ks) {
    float4 w = p4[idx + ks * (NTOK * DIM / 4)];
    v.x += w.x; v.y += w.y; v.z += w.z; v.w += w.w;
  }
  const float4 b = reinterpret_cast<const float4*>(bout)[idx % (DIM / 4)];
  v.x += b.x; v.y += b.y; v.z += b.z; v.w += b.w;
  reinterpret_cast<float4*>(out)[idx] = v;
}

// ---------------- launch ----------------
extern "C" void kernel_launch(void* const* d_in, const int* in_sizes, int n_in,
                              void* d_out, int out_size, void* d_ws, size_t ws_size,
                              hipStream_t stream) {
  const float* x     = (const float*)d_in[0];
  const float* pair  = (const float*)d_in[1];
  const float* rot   = (const float*)d_in[2];
  const float* trans = (const float*)d_in[3];
  const float* Wsq   = (const float*)d_in[4];
  const float* Wsk   = (const float*)d_in[5];
  const float* Wsv   = (const float*)d_in[6];
  const float* Wpq   = (const float*)d_in[7];
  const float* Wpk   = (const float*)d_in[8];
  const float* Wpv   = (const float*)d_in[9];
  const float* pw    = (const float*)d_in[10];
  const float* Wpair = (const float*)d_in[11];
  const float* bpair = (const float*)d_in[12];
  const float* Wout  = (const float*)d_in[13];
  const float* bout  = (const float*)d_in[14];
  float* out = (float*)d_out;

  float* ws = (float*)d_ws;
  float* qB = ws;                                     // 512*224
  float* kB = qB + (size_t)NTOK * QKB_STRIDE;         // 512*224
  float* vB = kB + (size_t)NTOK * QKB_STRIDE;         // 512*320
  float* results = vB + (size_t)NTOK * VB_STRIDE;     // 512*1408
  float* partial = results + (size_t)NTOK * RES_STRIDE;  // 512*8*1360 (~22.3 MB)
  float* pout = partial;                              // aliases partial (dead after combine)

  ipa_proj<<<dim3(NTOK / 4, 4), 192, 0, stream>>>(x, rot, trans, Wsq, Wsk, Wsv, Wpq, Wpk, Wpv, qB, kB, vB);
  ipa_attn_part<<<dim3(NC, NTOK), 256, 0, stream>>>(pair, pw, Wpair, bpair, qB, kB, vB, partial);
  ipa_combine<<<NTOK, 256, 0, stream>>>(partial, rot, trans, results);
  ipa_out1<<<dim3(NTOK / 32, DIM / 64, KS), 256, 0, stream>>>(results, Wout, pout);
  ipa_out2<<<NTOK * DIM / 4 / 256, 256, 0, stream>>>(pout, bout, out);
}